// Round 3
// baseline (14767.665 us; speedup 1.0000x reference)
//
#include <hip/hip_runtime.h>
#include <hip/hip_bf16.h>

// Sizes (fixed by the problem)
enum { B_ = 64, S_ = 32, V_ = 32000, HDIM = 768, NHEAD = 16, DHEAD = 48, NLAY = 3 };
#define LN_EPS 1e-5f

__device__ __forceinline__ float sigm(float x) { return 1.f / (1.f + expf(-x)); }

// ---------------------------------------------------------------------------
// Generic fp32 GEMM: C[M,N] = A[M,K] @ W[N,K]^T + bias  (ACC=1: C += ...)
// Tile 64(M) x TN(N), TN in {64,32}. K-step 16, 256 threads, thread 4 x (TN/16).
// Requires: M % 64 == 0, N % TN == 0, K % 16 == 0, lda/ldw % 4 == 0, 16B-aligned.
// TN=32 halves per-block work -> lower serial latency for tiny-M chains.
// ---------------------------------------------------------------------------
template <int ACC, int TN>
__global__ __launch_bounds__(256) void gemm_bias(const float* __restrict__ A, int lda,
                                                 const float* __restrict__ W, int ldw,
                                                 const float* __restrict__ bias,
                                                 float* __restrict__ C, int ldc, int K) {
    constexpr int JN = TN / 16;  // outputs per thread in N (4 or 2)
    __shared__ float As[16][68];
    __shared__ float Ws[16][TN + 4];
    const int tid = threadIdx.x;
    const int tx = tid & 15, ty = tid >> 4;
    const int m0 = blockIdx.y * 64, n0 = blockIdx.x * TN;
    const int lrow = tid >> 2;         // 0..63
    const int lk4 = (tid & 3) * 4;     // 0,4,8,12
    const bool wload = (TN == 64) || (tid < TN * 4);

    float acc[4][JN] = {};
    for (int k0 = 0; k0 < K; k0 += 16) {
        float4 av = *(const float4*)(A + (size_t)(m0 + lrow) * lda + k0 + lk4);
        float4 wv = make_float4(0.f, 0.f, 0.f, 0.f);
        if (wload) wv = *(const float4*)(W + (size_t)(n0 + lrow) * ldw + k0 + lk4);
        __syncthreads();
        As[lk4 + 0][lrow] = av.x; As[lk4 + 1][lrow] = av.y;
        As[lk4 + 2][lrow] = av.z; As[lk4 + 3][lrow] = av.w;
        if (wload) {
            Ws[lk4 + 0][lrow] = wv.x; Ws[lk4 + 1][lrow] = wv.y;
            Ws[lk4 + 2][lrow] = wv.z; Ws[lk4 + 3][lrow] = wv.w;
        }
        __syncthreads();
#pragma unroll
        for (int k = 0; k < 16; ++k) {
            float4 a4 = *(const float4*)&As[k][ty * 4];
            float a[4] = {a4.x, a4.y, a4.z, a4.w};
            float w[JN];
#pragma unroll
            for (int j = 0; j < JN; ++j) w[j] = Ws[k][tx * JN + j];
#pragma unroll
            for (int i = 0; i < 4; ++i)
#pragma unroll
                for (int j = 0; j < JN; ++j) acc[i][j] += a[i] * w[j];
        }
    }
#pragma unroll
    for (int i = 0; i < 4; ++i) {
        int m = m0 + ty * 4 + i;
#pragma unroll
        for (int j = 0; j < JN; ++j) {
            int n = n0 + tx * JN + j;
            float v = acc[i][j] + bias[n];
            if (ACC)
                C[(size_t)m * ldc + n] += v;
            else
                C[(size_t)m * ldc + n] = v;
        }
    }
}

// fus1 GEMM: A row m is concat(embeds[m, t, 0:512], ctx2[m, 0:768]); K=1280, N=768.
template <int TN>
__global__ __launch_bounds__(256) void gemm_fus1(const float* __restrict__ embeds,
                                                 const float* __restrict__ ctx2, int t,
                                                 const float* __restrict__ W,
                                                 const float* __restrict__ bias,
                                                 float* __restrict__ C) {
    constexpr int JN = TN / 16;
    __shared__ float As[16][68];
    __shared__ float Ws[16][TN + 4];
    const int tid = threadIdx.x;
    const int tx = tid & 15, ty = tid >> 4;
    const int n0 = blockIdx.x * TN;
    const int lrow = tid >> 2;
    const int lk4 = (tid & 3) * 4;
    const bool wload = (TN == 64) || (tid < TN * 4);

    float acc[4][JN] = {};
    for (int k0 = 0; k0 < 1280; k0 += 16) {
        int k = k0 + lk4;
        const float* src = (k < 512) ? (embeds + ((size_t)lrow * S_ + t) * 512 + k)
                                     : (ctx2 + (size_t)lrow * HDIM + (k - 512));
        float4 av = *(const float4*)src;
        float4 wv = make_float4(0.f, 0.f, 0.f, 0.f);
        if (wload) wv = *(const float4*)(W + (size_t)(n0 + lrow) * 1280 + k);
        __syncthreads();
        As[lk4 + 0][lrow] = av.x; As[lk4 + 1][lrow] = av.y;
        As[lk4 + 2][lrow] = av.z; As[lk4 + 3][lrow] = av.w;
        if (wload) {
            Ws[lk4 + 0][lrow] = wv.x; Ws[lk4 + 1][lrow] = wv.y;
            Ws[lk4 + 2][lrow] = wv.z; Ws[lk4 + 3][lrow] = wv.w;
        }
        __syncthreads();
#pragma unroll
        for (int kk = 0; kk < 16; ++kk) {
            float4 a4 = *(const float4*)&As[kk][ty * 4];
            float a[4] = {a4.x, a4.y, a4.z, a4.w};
            float w[JN];
#pragma unroll
            for (int j = 0; j < JN; ++j) w[j] = Ws[kk][tx * JN + j];
#pragma unroll
            for (int i = 0; i < 4; ++i)
#pragma unroll
                for (int j = 0; j < JN; ++j) acc[i][j] += a[i] * w[j];
        }
    }
#pragma unroll
    for (int i = 0; i < 4; ++i) {
        int m = ty * 4 + i;
#pragma unroll
        for (int j = 0; j < JN; ++j) {
            int n = n0 + tx * JN + j;
            C[(size_t)m * HDIM + n] = acc[i][j] + bias[n];
        }
    }
}

// Logits GEMM with output remap: A=(2048,768) rows r=t*64+b, W=(32000,768),
// out[b][t][n] = A@W^T + bias.
__global__ __launch_bounds__(256) void gemm_logits(const float* __restrict__ A,
                                                   const float* __restrict__ W,
                                                   const float* __restrict__ bias,
                                                   float* __restrict__ out) {
    __shared__ float As[16][68];
    __shared__ float Ws[16][68];
    const int tid = threadIdx.x;
    const int tx = tid & 15, ty = tid >> 4;
    const int m0 = blockIdx.y * 64, n0 = blockIdx.x * 64;
    const int lrow = tid >> 2;
    const int lk4 = (tid & 3) * 4;

    float acc[4][4] = {};
    for (int k0 = 0; k0 < HDIM; k0 += 16) {
        float4 av = *(const float4*)(A + (size_t)(m0 + lrow) * HDIM + k0 + lk4);
        float4 wv = *(const float4*)(W + (size_t)(n0 + lrow) * HDIM + k0 + lk4);
        __syncthreads();
        As[lk4 + 0][lrow] = av.x; As[lk4 + 1][lrow] = av.y;
        As[lk4 + 2][lrow] = av.z; As[lk4 + 3][lrow] = av.w;
        Ws[lk4 + 0][lrow] = wv.x; Ws[lk4 + 1][lrow] = wv.y;
        Ws[lk4 + 2][lrow] = wv.z; Ws[lk4 + 3][lrow] = wv.w;
        __syncthreads();
#pragma unroll
        for (int k = 0; k < 16; ++k) {
            float4 a4 = *(const float4*)&As[k][ty * 4];
            float4 w4 = *(const float4*)&Ws[k][tx * 4];
            float a[4] = {a4.x, a4.y, a4.z, a4.w};
            float w[4] = {w4.x, w4.y, w4.z, w4.w};
#pragma unroll
            for (int i = 0; i < 4; ++i)
#pragma unroll
                for (int j = 0; j < 4; ++j) acc[i][j] += a[i] * w[j];
        }
    }
#pragma unroll
    for (int i = 0; i < 4; ++i) {
        int m = m0 + ty * 4 + i;
        int tt = m >> 6, bb = m & 63;
#pragma unroll
        for (int j = 0; j < 4; ++j) {
            int n = n0 + tx * 4 + j;
            out[((size_t)bb * S_ + tt) * V_ + n] = acc[i][j] + bias[n];
        }
    }
}

// attn_feat (B,2048,7,7) -> feat (B*49, 2048)
__global__ __launch_bounds__(256) void transpose_feat(const float* __restrict__ af,
                                                      float* __restrict__ feat) {
    __shared__ float t[32][33];
    int b = blockIdx.z;
    int c0 = blockIdx.x * 32;
    int p0 = blockIdx.y * 32;
    int tx = threadIdx.x, ty = threadIdx.y;  // (32,8)
    const float* src = af + (size_t)b * 2048 * 49;
    for (int i = ty; i < 32; i += 8) {
        int c = c0 + i, p = p0 + tx;
        t[i][tx] = (p < 49) ? src[(size_t)c * 49 + p] : 0.f;
    }
    __syncthreads();
    float* dst = feat + (size_t)b * 49 * 2048;
    for (int i = ty; i < 32; i += 8) {
        int p = p0 + i, c = c0 + tx;
        if (p < 49) dst[(size_t)p * 2048 + c] = t[tx][i];
    }
}

// embeds gather: out[r, 0:512] = emb[ids[r], 0:512], r = b*S + t
__global__ void gather_emb(const int* __restrict__ ids, const float* __restrict__ emb,
                           float* __restrict__ out) {
    int r = blockIdx.x;
    int w = ids[r];
    const float* e = emb + (size_t)w * 512;
    float* o = out + (size_t)r * 512;
    for (int i = threadIdx.x; i < 512; i += 256) o[i] = e[i];
}

// Row-wise LayerNorm + activation (in-place safe). act: 0 none, 1 relu, 2 tanh.
__global__ __launch_bounds__(256) void ln_act(const float* __restrict__ X,
                                              const float* __restrict__ lnp,
                                              float* __restrict__ Y, int N, int act) {
    int r = blockIdx.x;
    const float* x = X + (size_t)r * N;
    float* y = Y + (size_t)r * N;
    float s1 = 0.f, s2 = 0.f;
    for (int i = threadIdx.x; i < N; i += 256) {
        float v = x[i];
        s1 += v;
        s2 += v * v;
    }
#pragma unroll
    for (int off = 32; off > 0; off >>= 1) {
        s1 += __shfl_down(s1, off, 64);
        s2 += __shfl_down(s2, off, 64);
    }
    __shared__ float a1[4], a2[4];
    __shared__ float mu_s, rs_s;
    int lane = threadIdx.x & 63, wid = threadIdx.x >> 6;
    if (lane == 0) { a1[wid] = s1; a2[wid] = s2; }
    __syncthreads();
    if (threadIdx.x == 0) {
        float S1 = a1[0] + a1[1] + a1[2] + a1[3];
        float S2 = a2[0] + a2[1] + a2[2] + a2[3];
        float mu = S1 / N;
        float var = S2 / N - mu * mu;
        mu_s = mu;
        rs_s = rsqrtf(var + LN_EPS);
    }
    __syncthreads();
    float mu = mu_s, rs = rs_s;
    for (int i = threadIdx.x; i < N; i += 256) {
        float v = (x[i] - mu) * rs * lnp[i] + lnp[N + i];
        if (act == 1) v = fmaxf(v, 0.f);
        else if (act == 2) v = tanhf(v);
        y[i] = v;
    }
}

// Fused attention for one (batch, head): scores = q.K*scale, softmax(49), ctx = w.V
__global__ __launch_bounds__(64) void attn_ctx(const float* __restrict__ q,
                                               const float* __restrict__ Kf,
                                               const float* __restrict__ Vf,
                                               float* __restrict__ ctx) {
    int b = blockIdx.x, h = blockIdx.y;
    int t = threadIdx.x;
    __shared__ float qs[48];
    __shared__ float w[49];
    if (t < 48) qs[t] = q[(size_t)b * HDIM + h * DHEAD + t];
    __syncthreads();
    if (t < 49) {
        const float* kr = Kf + (size_t)(b * 49 + t) * HDIM + h * DHEAD;
        float s = 0.f;
#pragma unroll
        for (int d = 0; d < 48; ++d) s += qs[d] * kr[d];
        w[t] = s * 0.14433756729740643f;  // 1/sqrt(48)
    }
    __syncthreads();
    if (t == 0) {
        float mx = w[0];
        for (int p = 1; p < 49; ++p) mx = fmaxf(mx, w[p]);
        float sum = 0.f;
        for (int p = 0; p < 49; ++p) {
            float e = expf(w[p] - mx);
            w[p] = e;
            sum += e;
        }
        float inv = 1.f / sum;
        for (int p = 0; p < 49; ++p) w[p] *= inv;
    }
    __syncthreads();
    if (t < 48) {
        float acc = 0.f;
        for (int p = 0; p < 49; ++p) acc += w[p] * Vf[(size_t)(b * 49 + p) * HDIM + h * DHEAD + t];
        ctx[(size_t)b * HDIM + h * DHEAD + t] = acc;
    }
}

// LSTM cell elementwise (gate order i,f,g,o). g: (64, 3072); c,h: (64*768) for this layer.
__global__ void lstm_cell(const float* __restrict__ g, float* __restrict__ c,
                          float* __restrict__ h, float* __restrict__ Hc, int t) {
    int idx = blockIdx.x * 256 + threadIdx.x;
    if (idx >= B_ * HDIM) return;
    int b = idx / HDIM, j = idx - b * HDIM;
    const float* gr = g + (size_t)b * 4 * HDIM;
    float iv = sigm(gr[j]);
    float fv = sigm(gr[HDIM + j]);
    float gv = tanhf(gr[2 * HDIM + j]);
    float ov = sigm(gr[3 * HDIM + j]);
    float cn = fv * c[idx] + iv * gv;
    float hn = ov * tanhf(cn);
    c[idx] = cn;
    h[idx] = hn;
    if (Hc) Hc[((size_t)t * B_ + b) * HDIM + j] = hn;
}

// Broadcast h0,c0 into all NL layers of state.
__global__ void tile_state(const float* __restrict__ h0, const float* __restrict__ c0,
                           float* __restrict__ h, float* __restrict__ c) {
    int idx = blockIdx.x * 256 + threadIdx.x;
    if (idx >= B_ * HDIM) return;
    float hv = h0[idx], cv = c0[idx];
#pragma unroll
    for (int l = 0; l < NLAY; ++l) {
        h[(size_t)l * B_ * HDIM + idx] = hv;
        c[(size_t)l * B_ * HDIM + idx] = cv;
    }
}

extern "C" void kernel_launch(void* const* d_in, const int* in_sizes, int n_in,
                              void* d_out, int out_size, void* d_ws, size_t ws_size,
                              hipStream_t stream) {
    const int* word_ids  = (const int*)d_in[0];
    const float* cnn     = (const float*)d_in[1];
    const float* attn_f  = (const float*)d_in[2];
    const float* emb     = (const float*)d_in[3];
    const float* af_w    = (const float*)d_in[4];
    const float* af_b    = (const float*)d_in[5];
    const float* qkv_w   = (const float*)d_in[6];
    const float* qkv_b   = (const float*)d_in[7];
    const float* o_w     = (const float*)d_in[8];
    const float* o_b     = (const float*)d_in[9];
    const float* attn_ln = (const float*)d_in[10];
    const float* fus_w1  = (const float*)d_in[11];
    const float* fus_b1  = (const float*)d_in[12];
    const float* fus_ln1 = (const float*)d_in[13];
    const float* fus_w2  = (const float*)d_in[14];
    const float* fus_b2  = (const float*)d_in[15];
    const float* fus_ln2 = (const float*)d_in[16];
    const float* wih     = (const float*)d_in[17];
    const float* whh     = (const float*)d_in[18];
    const float* bih     = (const float*)d_in[19];
    const float* bhh     = (const float*)d_in[20];
    const float* hi_w1   = (const float*)d_in[21];
    const float* hi_b1   = (const float*)d_in[22];
    const float* hi_ln1  = (const float*)d_in[23];
    const float* hi_w2   = (const float*)d_in[24];
    const float* hi_b2   = (const float*)d_in[25];
    const float* hi_ln2  = (const float*)d_in[26];
    const float* ci_w1   = (const float*)d_in[27];
    const float* ci_b1   = (const float*)d_in[28];
    const float* ci_ln1  = (const float*)d_in[29];
    const float* ci_w2   = (const float*)d_in[30];
    const float* ci_b2   = (const float*)d_in[31];
    const float* ci_ln2  = (const float*)d_in[32];
    const float* out_w1  = (const float*)d_in[33];
    const float* out_b1  = (const float*)d_in[34];
    const float* out_ln1 = (const float*)d_in[35];
    const float* out_w2  = (const float*)d_in[36];
    const float* out_b2  = (const float*)d_in[37];
    const float* out_ln2 = (const float*)d_in[38];
    const float* out_w3  = (const float*)d_in[39];
    const float* out_b3  = (const float*)d_in[40];
    float* outf = (float*)d_out;

    float* ws = (float*)d_ws;
    size_t off = 0;
    auto alloc = [&](size_t n) {
        float* p = ws + off;
        off += (n + 63) & ~(size_t)63;
        return p;
    };
    float* feat   = alloc((size_t)3136 * 2048);  // reused post-loop as Y1/Y2
    float* fp     = alloc((size_t)3136 * HDIM);  // reused in-loop as Hc
    float* Kf     = alloc((size_t)3136 * HDIM);
    float* Vf     = alloc((size_t)3136 * HDIM);
    float* emb_s  = alloc((size_t)B_ * S_ * 512);
    float* hst    = alloc((size_t)NLAY * B_ * HDIM);
    float* cst    = alloc((size_t)NLAY * B_ * HDIM);
    float* tmp1536= alloc((size_t)B_ * 1536);
    float* h0b    = alloc((size_t)B_ * HDIM);
    float* c0b    = alloc((size_t)B_ * HDIM);
    float* qb     = alloc((size_t)B_ * HDIM);
    float* ctxb   = alloc((size_t)B_ * HDIM);
    float* ctx2b  = alloc((size_t)B_ * HDIM);
    float* x1b    = alloc((size_t)B_ * HDIM);
    float* x2b    = alloc((size_t)B_ * HDIM);
    float* gb     = alloc((size_t)B_ * 4 * HDIM);
    if (off * sizeof(float) > ws_size) return;  // ws too small -> visible as wrong output

    float* Hc = fp;    // (2048, 768) collected top-layer h; fp no longer needed in loop
    float* Y1 = feat;  // (2048, 1536)
    float* Y2 = feat + (size_t)3200 * 1024;  // (2048, 768), still inside feat region

    const size_t WQKV = (size_t)HDIM * HDIM;  // 589824

    // ---- Precompute (timestep-independent) ----
    gather_emb<<<B_ * S_, 256, 0, stream>>>(word_ids, emb, emb_s);
    transpose_feat<<<dim3(64, 2, B_), dim3(32, 8), 0, stream>>>(attn_f, feat);
    // fp = feat @ af_w^T + af_b       (3136 x 768, K=2048)
    gemm_bias<0, 64><<<dim3(12, 49), 256, 0, stream>>>(feat, 2048, af_w, 2048, af_b, fp, HDIM, 2048);
    // K = fp @ Wk^T + bk ; V = fp @ Wv^T + bv   (3136 x 768, K=768)
    gemm_bias<0, 64><<<dim3(12, 49), 256, 0, stream>>>(fp, HDIM, qkv_w + WQKV, HDIM, qkv_b + HDIM, Kf, HDIM, HDIM);
    gemm_bias<0, 64><<<dim3(12, 49), 256, 0, stream>>>(fp, HDIM, qkv_w + 2 * WQKV, HDIM, qkv_b + 2 * HDIM, Vf, HDIM, HDIM);
    // h0 = tanh(LN(relu(LN(cnn@hi_w1^T+b)) @ hi_w2^T + b))
    gemm_bias<0, 64><<<dim3(24, 1), 256, 0, stream>>>(cnn, HDIM, hi_w1, HDIM, hi_b1, tmp1536, 1536, HDIM);
    ln_act<<<B_, 256, 0, stream>>>(tmp1536, hi_ln1, tmp1536, 1536, 1);
    gemm_bias<0, 64><<<dim3(12, 1), 256, 0, stream>>>(tmp1536, 1536, hi_w2, 1536, hi_b2, h0b, HDIM, 1536);
    ln_act<<<B_, 256, 0, stream>>>(h0b, hi_ln2, h0b, HDIM, 2);
    // c0 likewise
    gemm_bias<0, 64><<<dim3(24, 1), 256, 0, stream>>>(cnn, HDIM, ci_w1, HDIM, ci_b1, tmp1536, 1536, HDIM);
    ln_act<<<B_, 256, 0, stream>>>(tmp1536, ci_ln1, tmp1536, 1536, 1);
    gemm_bias<0, 64><<<dim3(12, 1), 256, 0, stream>>>(tmp1536, 1536, ci_w2, 1536, ci_b2, c0b, HDIM, 1536);
    ln_act<<<B_, 256, 0, stream>>>(c0b, ci_ln2, c0b, HDIM, 2);
    tile_state<<<192, 256, 0, stream>>>(h0b, c0b, hst, cst);

    // ---- Sequential recurrence (TN=32 tiles: 2x blocks, ~half serial latency) ----
    const size_t LBH = (size_t)B_ * HDIM;  // 49152
    for (int t = 0; t < S_; ++t) {
        // q = h[2] @ Wq^T + bq
        gemm_bias<0, 32><<<dim3(24, 1), 256, 0, stream>>>(hst + 2 * LBH, HDIM, qkv_w, HDIM, qkv_b, qb, HDIM, HDIM);
        attn_ctx<<<dim3(B_, NHEAD), 64, 0, stream>>>(qb, Kf, Vf, ctxb);
        gemm_bias<0, 32><<<dim3(24, 1), 256, 0, stream>>>(ctxb, HDIM, o_w, HDIM, o_b, ctx2b, HDIM, HDIM);
        ln_act<<<B_, 256, 0, stream>>>(ctx2b, attn_ln, ctx2b, HDIM, 0);
        gemm_fus1<32><<<dim3(24, 1), 256, 0, stream>>>(emb_s, ctx2b, t, fus_w1, fus_b1, x1b);
        ln_act<<<B_, 256, 0, stream>>>(x1b, fus_ln1, x1b, HDIM, 1);
        gemm_bias<0, 32><<<dim3(24, 1), 256, 0, stream>>>(x1b, HDIM, fus_w2, HDIM, fus_b2, x2b, HDIM, HDIM);
        ln_act<<<B_, 256, 0, stream>>>(x2b, fus_ln2, x2b, HDIM, 1);
        for (int l = 0; l < NLAY; ++l) {
            const float* inp = (l == 0) ? x2b : (hst + (size_t)(l - 1) * LBH);
            gemm_bias<0, 32><<<dim3(96, 1), 256, 0, stream>>>(inp, HDIM, wih + (size_t)l * 4 * HDIM * HDIM, HDIM,
                                                              bih + (size_t)l * 4 * HDIM, gb, 4 * HDIM, HDIM);
            gemm_bias<1, 32><<<dim3(96, 1), 256, 0, stream>>>(hst + (size_t)l * LBH, HDIM,
                                                              whh + (size_t)l * 4 * HDIM * HDIM, HDIM,
                                                              bhh + (size_t)l * 4 * HDIM, gb, 4 * HDIM, HDIM);
            lstm_cell<<<192, 256, 0, stream>>>(gb, cst + (size_t)l * LBH, hst + (size_t)l * LBH,
                                               (l == NLAY - 1) ? Hc : nullptr, t);
        }
    }

    // ---- Deferred output head (batched over all 2048 rows) ----
    gemm_bias<0, 64><<<dim3(24, 32), 256, 0, stream>>>(Hc, HDIM, out_w1, HDIM, out_b1, Y1, 1536, HDIM);
    ln_act<<<B_ * S_, 256, 0, stream>>>(Y1, out_ln1, Y1, 1536, 1);
    gemm_bias<0, 64><<<dim3(12, 32), 256, 0, stream>>>(Y1, 1536, out_w2, 1536, out_b2, Y2, HDIM, 1536);
    ln_act<<<B_ * S_, 256, 0, stream>>>(Y2, out_ln2, Y2, HDIM, 1);
    gemm_logits<<<dim3(500, 32), 256, 0, stream>>>(Y2, out_w3, out_b3, outf);

    // ---- Final states ----
    size_t ys_elems = (size_t)B_ * S_ * V_;
    hipMemcpyAsync(outf + ys_elems, hst, NLAY * LBH * sizeof(float), hipMemcpyDeviceToDevice, stream);
    hipMemcpyAsync(outf + ys_elems + NLAY * LBH, cst, NLAY * LBH * sizeof(float), hipMemcpyDeviceToDevice, stream);
}

// Round 5
// 8965.323 us; speedup vs baseline: 1.6472x; 1.6472x over previous
//
#include <hip/hip_runtime.h>
#include <hip/hip_bf16.h>

// Sizes (fixed by the problem)
enum { B_ = 64, S_ = 32, V_ = 32000, HDIM = 768, NHEAD = 16, DHEAD = 48, NLAY = 3 };
#define LN_EPS 1e-5f

typedef __bf16 bf16_t;
typedef __bf16 bf8 __attribute__((ext_vector_type(8)));
typedef __bf16 bf4v __attribute__((ext_vector_type(4)));
typedef float f4 __attribute__((ext_vector_type(4)));

__device__ __forceinline__ float sigm(float x) { return 1.f / (1.f + expf(-x)); }

__device__ __forceinline__ f4 mfma16x16x32(bf8 a, bf8 b, f4 c) {
    return __builtin_amdgcn_mfma_f32_16x16x32_bf16(a, b, c, 0, 0, 0);
}

// ---------------------------------------------------------------------------
// f32 -> bf16 cast, vectorized x4. n4 = elems/4.
// ---------------------------------------------------------------------------
__global__ __launch_bounds__(256) void cast_bf16_4(const float4* __restrict__ x,
                                                   bf4v* __restrict__ y, int n4) {
    int i = blockIdx.x * 256 + threadIdx.x;
    int st = gridDim.x * 256;
    for (; i < n4; i += st) {
        float4 v = x[i];
        bf4v o;
        o.x = (__bf16)v.x; o.y = (__bf16)v.y; o.z = (__bf16)v.z; o.w = (__bf16)v.w;
        y[i] = o;
    }
}

// ---------------------------------------------------------------------------
// MFMA GEMM: C[M,N] = A[M,K](bf16) @ W[N,K](bf16)^T + bias(f32).
// grid = (N/64, M/64), 256 thr = 4 waves; wave w owns rows m0+16w..+15.
// Fragments loaded directly from global (weights are L2/L3-resident).
// A/B frag: lane l holds 8 contig K-elems of row (l&15) at k=(l>>4)*8.
// C/D frag: col = lane&15, row = (lane>>4)*4 + reg.
// OUTBF: write C as bf16. REMAP: logits row remap m=t*64+b -> out[(b*S+t)*V+n].
// ---------------------------------------------------------------------------
template <int OUTBF, int REMAP>
__global__ __launch_bounds__(256) void gemm_mf(const bf16_t* __restrict__ A, int lda,
                                               const bf16_t* __restrict__ W, int ldw,
                                               const float* __restrict__ bias,
                                               void* __restrict__ Cv, int ldc, int K) {
    const int lane = threadIdx.x & 63, wv = threadIdx.x >> 6;
    const int r = lane & 15, kg = lane >> 4;
    const int m0 = blockIdx.y * 64 + wv * 16;
    const int n0 = blockIdx.x * 64;
    const bf16_t* Ar = A + (size_t)(m0 + r) * lda + kg * 8;
    const bf16_t* W0 = W + (size_t)(n0 + r) * ldw + kg * 8;
    f4 acc[4] = {};
#pragma unroll 2
    for (int k0 = 0; k0 < K; k0 += 32) {
        bf8 a = *(const bf8*)(Ar + k0);
#pragma unroll
        for (int j = 0; j < 4; ++j) {
            bf8 b = *(const bf8*)(W0 + (size_t)j * 16 * ldw + k0);
            acc[j] = mfma16x16x32(a, b, acc[j]);
        }
    }
#pragma unroll
    for (int j = 0; j < 4; ++j) {
        int n = n0 + j * 16 + r;
        float bz = bias[n];
#pragma unroll
        for (int i = 0; i < 4; ++i) {
            int m = m0 + kg * 4 + i;
            float v = acc[j][i] + bz;
            if (REMAP) {
                int tt = m >> 6, bb = m & 63;
                ((float*)Cv)[((size_t)bb * S_ + tt) * V_ + n] = v;
            } else if (OUTBF) {
                ((bf16_t*)Cv)[(size_t)m * ldc + n] = (__bf16)v;
            } else {
                ((float*)Cv)[(size_t)m * ldc + n] = v;
            }
        }
    }
}

// LSTM gate GEMM: G[64,3072] = X@Wih^T + H@Whh^T + bih + bhh. K=768 both.
__global__ __launch_bounds__(256) void gemm_lstm(const bf16_t* __restrict__ X,
                                                 const bf16_t* __restrict__ Wih,
                                                 const bf16_t* __restrict__ H,
                                                 const bf16_t* __restrict__ Whh,
                                                 const float* __restrict__ b1,
                                                 const float* __restrict__ b2,
                                                 float* __restrict__ G) {
    const int lane = threadIdx.x & 63, wv = threadIdx.x >> 6;
    const int r = lane & 15, kg = lane >> 4;
    const int m0 = wv * 16;
    const int n0 = blockIdx.x * 64;
    const bf16_t* Xr = X + (size_t)(m0 + r) * HDIM + kg * 8;
    const bf16_t* Hr = H + (size_t)(m0 + r) * HDIM + kg * 8;
    const bf16_t* Wi = Wih + (size_t)(n0 + r) * HDIM + kg * 8;
    const bf16_t* Wh = Whh + (size_t)(n0 + r) * HDIM + kg * 8;
    f4 acc[4] = {};
#pragma unroll 2
    for (int k0 = 0; k0 < HDIM; k0 += 32) {
        bf8 ax = *(const bf8*)(Xr + k0);
        bf8 ah = *(const bf8*)(Hr + k0);
#pragma unroll
        for (int j = 0; j < 4; ++j) {
            acc[j] = mfma16x16x32(ax, *(const bf8*)(Wi + (size_t)j * 16 * HDIM + k0), acc[j]);
            acc[j] = mfma16x16x32(ah, *(const bf8*)(Wh + (size_t)j * 16 * HDIM + k0), acc[j]);
        }
    }
#pragma unroll
    for (int j = 0; j < 4; ++j) {
        int n = n0 + j * 16 + r;
        float bz = b1[n] + b2[n];
#pragma unroll
        for (int i = 0; i < 4; ++i) {
            int m = m0 + kg * 4 + i;
            G[(size_t)m * (4 * HDIM) + n] = acc[j][i] + bz;
        }
    }
}

// fus1 GEMM: A row m = concat(embB[(m*S+t)*512 ..], ctxB[m*768 ..]); K=1280, N=768.
__global__ __launch_bounds__(256) void gemm_fus1(const bf16_t* __restrict__ embB,
                                                 const bf16_t* __restrict__ ctxB, int t,
                                                 const bf16_t* __restrict__ W,
                                                 const float* __restrict__ bias,
                                                 float* __restrict__ C) {
    const int lane = threadIdx.x & 63, wv = threadIdx.x >> 6;
    const int r = lane & 15, kg = lane >> 4;
    const int m0 = wv * 16;
    const int n0 = blockIdx.x * 64;
    const int mr = m0 + r;
    const bf16_t* W0 = W + (size_t)(n0 + r) * 1280 + kg * 8;
    const bf16_t* eRow = embB + ((size_t)mr * S_ + t) * 512 + kg * 8;
    const bf16_t* cRow = ctxB + (size_t)mr * HDIM + kg * 8;
    f4 acc[4] = {};
#pragma unroll 2
    for (int k0 = 0; k0 < 1280; k0 += 32) {
        bf8 a = (k0 < 512) ? *(const bf8*)(eRow + k0) : *(const bf8*)(cRow + (k0 - 512));
#pragma unroll
        for (int j = 0; j < 4; ++j) {
            bf8 b = *(const bf8*)(W0 + (size_t)j * 16 * 1280 + k0);
            acc[j] = mfma16x16x32(a, b, acc[j]);
        }
    }
#pragma unroll
    for (int j = 0; j < 4; ++j) {
        int n = n0 + j * 16 + r;
        float bz = bias[n];
#pragma unroll
        for (int i = 0; i < 4; ++i) {
            int m = m0 + kg * 4 + i;
            C[(size_t)m * HDIM + n] = acc[j][i] + bz;
        }
    }
}

// attn_feat (B,2048,7,7) f32 -> featb (B*49, 2048) bf16
__global__ __launch_bounds__(256) void transpose_feat(const float* __restrict__ af,
                                                      bf16_t* __restrict__ feat) {
    __shared__ float t[32][33];
    int b = blockIdx.z;
    int c0 = blockIdx.x * 32;
    int p0 = blockIdx.y * 32;
    int tx = threadIdx.x, ty = threadIdx.y;  // (32,8)
    const float* src = af + (size_t)b * 2048 * 49;
    for (int i = ty; i < 32; i += 8) {
        int c = c0 + i, p = p0 + tx;
        t[i][tx] = (p < 49) ? src[(size_t)c * 49 + p] : 0.f;
    }
    __syncthreads();
    bf16_t* dst = feat + (size_t)b * 49 * 2048;
    for (int i = ty; i < 32; i += 8) {
        int p = p0 + i, c = c0 + tx;
        if (p < 49) dst[(size_t)p * 2048 + c] = (__bf16)t[tx][i];
    }
}

// embeds gather -> bf16: out[r,0:512] = emb[ids[r],0:512]
__global__ void gather_emb(const int* __restrict__ ids, const float* __restrict__ emb,
                           bf16_t* __restrict__ out) {
    int r = blockIdx.x;
    int w = ids[r];
    const float* e = emb + (size_t)w * 512;
    bf16_t* o = out + (size_t)r * 512;
    for (int i = threadIdx.x; i < 512; i += 256) o[i] = (__bf16)e[i];
}

// Row-wise LayerNorm + activation, f32 in/out + optional bf16 out.
__global__ __launch_bounds__(256) void ln_act(const float* __restrict__ X,
                                              const float* __restrict__ lnp,
                                              float* __restrict__ Y,
                                              bf16_t* __restrict__ Yb, int N, int act) {
    int r = blockIdx.x;
    const float* x = X + (size_t)r * N;
    float* y = Y + (size_t)r * N;
    bf16_t* yb = Yb ? (Yb + (size_t)r * N) : nullptr;
    float s1 = 0.f, s2 = 0.f;
    for (int i = threadIdx.x; i < N; i += 256) {
        float v = x[i];
        s1 += v;
        s2 += v * v;
    }
#pragma unroll
    for (int off = 32; off > 0; off >>= 1) {
        s1 += __shfl_down(s1, off, 64);
        s2 += __shfl_down(s2, off, 64);
    }
    __shared__ float a1[4], a2[4];
    __shared__ float mu_s, rs_s;
    int lane = threadIdx.x & 63, wid = threadIdx.x >> 6;
    if (lane == 0) { a1[wid] = s1; a2[wid] = s2; }
    __syncthreads();
    if (threadIdx.x == 0) {
        float S1 = a1[0] + a1[1] + a1[2] + a1[3];
        float S2 = a2[0] + a2[1] + a2[2] + a2[3];
        float mu = S1 / N;
        float var = S2 / N - mu * mu;
        mu_s = mu;
        rs_s = rsqrtf(var + LN_EPS);
    }
    __syncthreads();
    float mu = mu_s, rs = rs_s;
    for (int i = threadIdx.x; i < N; i += 256) {
        float v = (x[i] - mu) * rs * lnp[i] + lnp[N + i];
        if (act == 1) v = fmaxf(v, 0.f);
        else if (act == 2) v = tanhf(v);
        y[i] = v;
        if (yb) yb[i] = (__bf16)v;
    }
}

// Fused attention per (batch, head): softmax(q.K*scale).V -> ctx (bf16)
__global__ __launch_bounds__(64) void attn_ctx(const float* __restrict__ q,
                                               const float* __restrict__ Kf,
                                               const float* __restrict__ Vf,
                                               bf16_t* __restrict__ ctx) {
    int b = blockIdx.x, h = blockIdx.y;
    int t = threadIdx.x;
    __shared__ float qs[48];
    __shared__ float w[49];
    if (t < 48) qs[t] = q[(size_t)b * HDIM + h * DHEAD + t];
    __syncthreads();
    if (t < 49) {
        const float* kr = Kf + (size_t)(b * 49 + t) * HDIM + h * DHEAD;
        float s = 0.f;
#pragma unroll
        for (int d = 0; d < 48; ++d) s += qs[d] * kr[d];
        w[t] = s * 0.14433756729740643f;  // 1/sqrt(48)
    }
    __syncthreads();
    if (t == 0) {
        float mx = w[0];
        for (int p = 1; p < 49; ++p) mx = fmaxf(mx, w[p]);
        float sum = 0.f;
        for (int p = 0; p < 49; ++p) {
            float e = expf(w[p] - mx);
            w[p] = e;
            sum += e;
        }
        float inv = 1.f / sum;
        for (int p = 0; p < 49; ++p) w[p] *= inv;
    }
    __syncthreads();
    if (t < 48) {
        float acc = 0.f;
        for (int p = 0; p < 49; ++p) acc += w[p] * Vf[(size_t)(b * 49 + p) * HDIM + h * DHEAD + t];
        ctx[(size_t)b * HDIM + h * DHEAD + t] = (__bf16)acc;
    }
}

// LSTM cell: g(64,3072) f32 -> c f32 (state), h f32 + bf16, optional top-layer collect (bf16).
__global__ void lstm_cell(const float* __restrict__ g, float* __restrict__ c,
                          float* __restrict__ h, bf16_t* __restrict__ hb,
                          bf16_t* __restrict__ Hcb, int t) {
    int idx = blockIdx.x * 256 + threadIdx.x;
    if (idx >= B_ * HDIM) return;
    int b = idx / HDIM, j = idx - b * HDIM;
    const float* gr = g + (size_t)b * 4 * HDIM;
    float iv = sigm(gr[j]);
    float fv = sigm(gr[HDIM + j]);
    float gv = tanhf(gr[2 * HDIM + j]);
    float ov = sigm(gr[3 * HDIM + j]);
    float cn = fv * c[idx] + iv * gv;
    float hn = ov * tanhf(cn);
    c[idx] = cn;
    h[idx] = hn;
    hb[idx] = (__bf16)hn;
    if (Hcb) Hcb[((size_t)t * B_ + b) * HDIM + j] = (__bf16)hn;
}

// Broadcast h0,c0 into all NL layers (f32 state + bf16 h).
__global__ void tile_state(const float* __restrict__ h0, const float* __restrict__ c0,
                           float* __restrict__ h, float* __restrict__ c,
                           bf16_t* __restrict__ hb) {
    int idx = blockIdx.x * 256 + threadIdx.x;
    if (idx >= B_ * HDIM) return;
    float hv = h0[idx], cv = c0[idx];
#pragma unroll
    for (int l = 0; l < NLAY; ++l) {
        h[(size_t)l * B_ * HDIM + idx] = hv;
        c[(size_t)l * B_ * HDIM + idx] = cv;
        hb[(size_t)l * B_ * HDIM + idx] = (__bf16)hv;
    }
}

extern "C" void kernel_launch(void* const* d_in, const int* in_sizes, int n_in,
                              void* d_out, int out_size, void* d_ws, size_t ws_size,
                              hipStream_t stream) {
    const int* word_ids  = (const int*)d_in[0];
    const float* cnn     = (const float*)d_in[1];
    const float* attn_f  = (const float*)d_in[2];
    const float* emb     = (const float*)d_in[3];
    const float* af_w    = (const float*)d_in[4];
    const float* af_b    = (const float*)d_in[5];
    const float* qkv_w   = (const float*)d_in[6];
    const float* qkv_b   = (const float*)d_in[7];
    const float* o_w     = (const float*)d_in[8];
    const float* o_b     = (const float*)d_in[9];
    const float* attn_ln = (const float*)d_in[10];
    const float* fus_w1  = (const float*)d_in[11];
    const float* fus_b1  = (const float*)d_in[12];
    const float* fus_ln1 = (const float*)d_in[13];
    const float* fus_w2  = (const float*)d_in[14];
    const float* fus_b2  = (const float*)d_in[15];
    const float* fus_ln2 = (const float*)d_in[16];
    const float* wih     = (const float*)d_in[17];
    const float* whh     = (const float*)d_in[18];
    const float* bih     = (const float*)d_in[19];
    const float* bhh     = (const float*)d_in[20];
    const float* hi_w1   = (const float*)d_in[21];
    const float* hi_b1   = (const float*)d_in[22];
    const float* hi_ln1  = (const float*)d_in[23];
    const float* hi_w2   = (const float*)d_in[24];
    const float* hi_b2   = (const float*)d_in[25];
    const float* hi_ln2  = (const float*)d_in[26];
    const float* ci_w1   = (const float*)d_in[27];
    const float* ci_b1   = (const float*)d_in[28];
    const float* ci_ln1  = (const float*)d_in[29];
    const float* ci_w2   = (const float*)d_in[30];
    const float* ci_b2   = (const float*)d_in[31];
    const float* ci_ln2  = (const float*)d_in[32];
    const float* out_w1  = (const float*)d_in[33];
    const float* out_b1  = (const float*)d_in[34];
    const float* out_ln1 = (const float*)d_in[35];
    const float* out_w2  = (const float*)d_in[36];
    const float* out_b2  = (const float*)d_in[37];
    const float* out_ln2 = (const float*)d_in[38];
    const float* out_w3  = (const float*)d_in[39];
    const float* out_b3  = (const float*)d_in[40];
    float* outf = (float*)d_out;

    // ---- workspace carve (bytes, 256B aligned) ----
    char* wsb = (char*)d_ws;
    size_t off = 0;
    auto allocB = [&](size_t bytes) {
        char* p = wsb + off;
        off += (bytes + 255) & ~(size_t)255;
        return p;
    };
    auto allocF = [&](size_t n) { return (float*)allocB(n * 4); };
    auto allocH = [&](size_t n) { return (bf16_t*)allocB(n * 2); };

    // bf16 buffers
    bf16_t* featb  = allocH((size_t)3136 * 2048);  // reused post-loop: HcB/Y1B/Y2B
    bf16_t* fpb    = allocH((size_t)3136 * HDIM);
    bf16_t* emb_sb = allocH((size_t)B_ * S_ * 512);
    bf16_t* af_wb  = allocH((size_t)HDIM * 2048);
    bf16_t* qkv_wb = allocH((size_t)3 * HDIM * HDIM);
    bf16_t* o_wb   = allocH((size_t)HDIM * HDIM);
    bf16_t* fus_w1b= allocH((size_t)HDIM * 1280);
    bf16_t* fus_w2b= allocH((size_t)HDIM * HDIM);
    bf16_t* wihb   = allocH((size_t)NLAY * 4 * HDIM * HDIM);
    bf16_t* whhb   = allocH((size_t)NLAY * 4 * HDIM * HDIM);
    bf16_t* hi_w1b = allocH((size_t)1536 * HDIM);
    bf16_t* hi_w2b = allocH((size_t)HDIM * 1536);
    bf16_t* ci_w1b = allocH((size_t)1536 * HDIM);
    bf16_t* ci_w2b = allocH((size_t)HDIM * 1536);
    bf16_t* out_w1b= allocH((size_t)1536 * HDIM);
    bf16_t* out_w2b= allocH((size_t)HDIM * 1536);
    bf16_t* out_w3b= allocH((size_t)V_ * HDIM);
    bf16_t* cnnb   = allocH((size_t)B_ * HDIM);
    bf16_t* hstb   = allocH((size_t)NLAY * B_ * HDIM);
    bf16_t* tmpB   = allocH((size_t)B_ * 1536);
    bf16_t* ctxB   = allocH((size_t)B_ * HDIM);
    bf16_t* ctx2B  = allocH((size_t)B_ * HDIM);
    bf16_t* x1B    = allocH((size_t)B_ * HDIM);
    bf16_t* x2B    = allocH((size_t)B_ * HDIM);
    // f32 buffers
    float* Kf      = allocF((size_t)3136 * HDIM);
    float* Vf      = allocF((size_t)3136 * HDIM);
    float* hst     = allocF((size_t)NLAY * B_ * HDIM);
    float* cst     = allocF((size_t)NLAY * B_ * HDIM);
    float* tmp1536 = allocF((size_t)B_ * 1536);
    float* h0b     = allocF((size_t)B_ * HDIM);
    float* c0b     = allocF((size_t)B_ * HDIM);
    float* qb      = allocF((size_t)B_ * HDIM);
    float* ctx2f   = allocF((size_t)B_ * HDIM);
    float* x1f     = allocF((size_t)B_ * HDIM);
    float* x2f     = allocF((size_t)B_ * HDIM);
    float* gb      = allocF((size_t)B_ * 4 * HDIM);
    float* Y1f     = allocF((size_t)2048 * 1536);  // Y2f aliases front half after Y1f dead
    if (off > ws_size) return;  // visible failure if ws too small

    // post-loop bf16 heads carved inside featb (dead after K/V precompute)
    bf16_t* HcB = featb;                                   // 2048*768
    bf16_t* Y1B = featb + (size_t)2048 * HDIM;             // 2048*1536
    bf16_t* Y2B = Y1B + (size_t)2048 * 1536;               // 2048*768  (total 6.29M <= 6.42M)
    float*  Y2f = Y1f;                                     // alias: Y1f dead after its LN

    const size_t WQKV = (size_t)HDIM * HDIM;
    const size_t LBH = (size_t)B_ * HDIM;

    auto cast = [&](const float* src, bf16_t* dst, size_t n) {
        int n4 = (int)(n / 4);
        int blocks = (n4 + 255) / 256;
        if (blocks > 1024) blocks = 1024;
        cast_bf16_4<<<blocks, 256, 0, stream>>>((const float4*)src, (bf4v*)dst, n4);
    };

    // ---- weight casts ----
    cast(af_w,   af_wb,   (size_t)HDIM * 2048);
    cast(qkv_w,  qkv_wb,  (size_t)3 * HDIM * HDIM);
    cast(o_w,    o_wb,    (size_t)HDIM * HDIM);
    cast(fus_w1, fus_w1b, (size_t)HDIM * 1280);
    cast(fus_w2, fus_w2b, (size_t)HDIM * HDIM);
    cast(wih,    wihb,    (size_t)NLAY * 4 * HDIM * HDIM);
    cast(whh,    whhb,    (size_t)NLAY * 4 * HDIM * HDIM);
    cast(hi_w1,  hi_w1b,  (size_t)1536 * HDIM);
    cast(hi_w2,  hi_w2b,  (size_t)HDIM * 1536);
    cast(ci_w1,  ci_w1b,  (size_t)1536 * HDIM);
    cast(ci_w2,  ci_w2b,  (size_t)HDIM * 1536);
    cast(out_w1, out_w1b, (size_t)1536 * HDIM);
    cast(out_w2, out_w2b, (size_t)HDIM * 1536);
    cast(out_w3, out_w3b, (size_t)V_ * HDIM);
    cast(cnn,    cnnb,    (size_t)B_ * HDIM);

    // ---- precompute ----
    gather_emb<<<B_ * S_, 256, 0, stream>>>(word_ids, emb, emb_sb);
    transpose_feat<<<dim3(64, 2, B_), dim3(32, 8), 0, stream>>>(attn_f, featb);
    // fp(bf16) = featb @ af_w^T + af_b   (3136x768, K=2048)
    gemm_mf<1, 0><<<dim3(12, 49), 256, 0, stream>>>(featb, 2048, af_wb, 2048, af_b, fpb, HDIM, 2048);
    // K,V (f32) = fp @ Wk/Wv^T + b      (3136x768, K=768)
    gemm_mf<0, 0><<<dim3(12, 49), 256, 0, stream>>>(fpb, HDIM, qkv_wb + WQKV, HDIM, qkv_b + HDIM, Kf, HDIM, HDIM);
    gemm_mf<0, 0><<<dim3(12, 49), 256, 0, stream>>>(fpb, HDIM, qkv_wb + 2 * WQKV, HDIM, qkv_b + 2 * HDIM, Vf, HDIM, HDIM);
    // h0 = tanh(LN(relu(LN(cnn@hi_w1^T+b))@hi_w2^T+b))
    gemm_mf<0, 0><<<dim3(24, 1), 256, 0, stream>>>(cnnb, HDIM, hi_w1b, HDIM, hi_b1, tmp1536, 1536, HDIM);
    ln_act<<<B_, 256, 0, stream>>>(tmp1536, hi_ln1, tmp1536, tmpB, 1536, 1);
    gemm_mf<0, 0><<<dim3(12, 1), 256, 0, stream>>>(tmpB, 1536, hi_w2b, 1536, hi_b2, h0b, HDIM, 1536);
    ln_act<<<B_, 256, 0, stream>>>(h0b, hi_ln2, h0b, nullptr, HDIM, 2);
    // c0
    gemm_mf<0, 0><<<dim3(24, 1), 256, 0, stream>>>(cnnb, HDIM, ci_w1b, HDIM, ci_b1, tmp1536, 1536, HDIM);
    ln_act<<<B_, 256, 0, stream>>>(tmp1536, ci_ln1, tmp1536, tmpB, 1536, 1);
    gemm_mf<0, 0><<<dim3(12, 1), 256, 0, stream>>>(tmpB, 1536, ci_w2b, 1536, ci_b2, c0b, HDIM, 1536);
    ln_act<<<B_, 256, 0, stream>>>(c0b, ci_ln2, c0b, nullptr, HDIM, 2);
    tile_state<<<192, 256, 0, stream>>>(h0b, c0b, hst, cst, hstb);

    // ---- sequential recurrence ----
    for (int t = 0; t < S_; ++t) {
        gemm_mf<0, 0><<<dim3(12, 1), 256, 0, stream>>>(hstb + 2 * LBH, HDIM, qkv_wb, HDIM, qkv_b, qb, HDIM, HDIM);
        attn_ctx<<<dim3(B_, NHEAD), 64, 0, stream>>>(qb, Kf, Vf, ctxB);
        gemm_mf<0, 0><<<dim3(12, 1), 256, 0, stream>>>(ctxB, HDIM, o_wb, HDIM, o_b, ctx2f, HDIM, HDIM);
        ln_act<<<B_, 256, 0, stream>>>(ctx2f, attn_ln, ctx2f, ctx2B, HDIM, 0);
        gemm_fus1<<<dim3(12, 1), 256, 0, stream>>>(emb_sb, ctx2B, t, fus_w1b, fus_b1, x1f);
        ln_act<<<B_, 256, 0, stream>>>(x1f, fus_ln1, x1f, x1B, HDIM, 1);
        gemm_mf<0, 0><<<dim3(12, 1), 256, 0, stream>>>(x1B, HDIM, fus_w2b, HDIM, fus_b2, x2f, HDIM, HDIM);
        ln_act<<<B_, 256, 0, stream>>>(x2f, fus_ln2, x2f, x2B, HDIM, 1);
        for (int l = 0; l < NLAY; ++l) {
            const bf16_t* inp = (l == 0) ? x2B : (hstb + (size_t)(l - 1) * LBH);
            gemm_lstm<<<dim3(48, 1), 256, 0, stream>>>(inp,
                                                       wihb + (size_t)l * 4 * HDIM * HDIM,
                                                       hstb + (size_t)l * LBH,
                                                       whhb + (size_t)l * 4 * HDIM * HDIM,
                                                       bih + (size_t)l * 4 * HDIM,
                                                       bhh + (size_t)l * 4 * HDIM, gb);
            lstm_cell<<<192, 256, 0, stream>>>(gb, cst + (size_t)l * LBH, hst + (size_t)l * LBH,
                                               hstb + (size_t)l * LBH,
                                               (l == NLAY - 1) ? HcB : nullptr, t);
        }
    }

    // ---- deferred output head (2048 rows batched) ----
    gemm_mf<0, 0><<<dim3(24, 32), 256, 0, stream>>>(HcB, HDIM, out_w1b, HDIM, out_b1, Y1f, 1536, HDIM);
    ln_act<<<B_ * S_, 256, 0, stream>>>(Y1f, out_ln1, Y1f, Y1B, 1536, 1);
    gemm_mf<0, 0><<<dim3(12, 32), 256, 0, stream>>>(Y1B, 1536, out_w2b, 1536, out_b2, Y2f, HDIM, 1536);
    ln_act<<<B_ * S_, 256, 0, stream>>>(Y2f, out_ln2, Y2f, Y2B, HDIM, 1);
    gemm_mf<0, 1><<<dim3(500, 32), 256, 0, stream>>>(Y2B, HDIM, out_w3b, HDIM, out_b3, outf, V_, HDIM);

    // ---- final states ----
    size_t ys_elems = (size_t)B_ * S_ * V_;
    hipMemcpyAsync(outf + ys_elems, hst, NLAY * LBH * sizeof(float), hipMemcpyDeviceToDevice, stream);
    hipMemcpyAsync(outf + ys_elems + NLAY * LBH, cst, NLAY * LBH * sizeof(float), hipMemcpyDeviceToDevice, stream);
}